// Round 28
// baseline (25.985 us; speedup 1.0000x reference)
//
#include <hip/hip_runtime.h>
#include <hip/hip_bf16.h>

// Problem constants (from reference)
#define B 8
#define C 64
#define H 64
#define W 64
#define K 5
#define PAD 2
#define HW (H * W)          // 4096
#define CHW (C * HW)        // 262144
#define TOT (B * CHW)       // 2097152

// row-padded k/v planes: [68 rows][64 cols]; global row g at padded row g+2;
// rows 0,1,66,67 are zero (written by qkv's pad-zero step)
#define PROWS4 68
#define PHW4 (PROWS4 * W)   // 4352

// attn tiling (r21 shape): block = 8 rows x 64 cols; 2 px/thread; 4096 blocks
#define TROWS3 8
#define SROWS3 (TROWS3 + 2 * PAD)  // 12 staged rows
#define SCOLS 72                   // 64 + 2*PAD padded to 72 (16B row align)

#define LOG2E 1.44269504088896340736f

typedef __attribute__((ext_vector_type(8))) short short8;   // 8 bf16 = 4 VGPR
typedef __attribute__((ext_vector_type(4))) float f32x4;    // mfma accum
typedef __attribute__((ext_vector_type(2))) float f32x2;    // packed fp32

// native bf16 conversion (RNE; pairs lower to v_cvt_pk_bf16_f32)
__device__ inline unsigned short f2bf(float f) {
    __hip_bfloat16 h = __float2bfloat16(f);
    return *(unsigned short*)&h;
}
__device__ inline float bf2f(unsigned short u) {
    return __uint_as_float(((unsigned)u) << 16);
}

// raw v_exp_f32 (single instruction; inputs in [-40,40])
__device__ inline float fast_exp2(float x) {
    return __builtin_amdgcn_exp2f(x);
}

// ---------------------------------------------------------------------------
// Pass 1 (v13): qkv MFMA GEMM — r27 structure with ROW-PADDED k/v outputs:
// k/v planes are [68][64] (pad rows 0,1,66,67 zero; interior at +2 rows).
// Each block additionally zeroes ONE plane's 4 pad rows (1 dword store per
// thread, issued before the stage so it overlaps).  Same store count for
// the epilogue (stride PHW4, offset +128).  q unpadded, pre-scaled log2(e).
// ---------------------------------------------------------------------------
__global__ __launch_bounds__(256) void qkv_mfma(
    const float* __restrict__ x,
    const float* __restrict__ Wq,
    const float* __restrict__ Wk,
    const float* __restrict__ Wv,
    float* __restrict__ qb, float* __restrict__ kb, float* __restrict__ vb)
{
    __shared__ unsigned short sxh[32][72];   // [n][k], 4.6 KB
    __shared__ unsigned short sxl[32][72];

    const int bid = blockIdx.x;
    const int b   = bid & 7;             // XCD co-residency: batch = XCD
    const int n0  = (bid >> 3) * 32;     // hw base (128 chunks per batch)
    const int t   = threadIdx.x;

    // ---- pad-row zero: block bid owns one (k or v) plane of its batch ----
    {
        const int pidx = bid >> 3;           // 0..127
        const int cz   = pidx >> 1;          // channel 0..63
        float* pz = ((pidx & 1) ? vb : kb) + (b * C + cz) * PHW4;
        // rows 0,1 = offsets 0..127 ; rows 66,67 = offsets 4224..4351
        const int off = (t < 128) ? t : (4224 - 128 + t);
        pz[off] = 0.f;
    }

    const int lane = t & 63;
    const int wv   = __builtin_amdgcn_readfirstlane(t >> 6);  // wave id 0..3
    const int lr   = lane & 15;          // tile row (A) / col (B,D)
    const int lk   = (lane >> 4) * 8;    // k-group base

    // ---- A fragments FIRST (overlaps the x stage-load latency below) ----
    short8 ah[3][2], al[3][2];
#pragma unroll
    for (int ot = 0; ot < 3; ++ot) {
        const int tile = wv * 3 + ot;            // 0..11
        const int m    = tile >> 2;              // 0=q,1=k,2=v
        const int ol0  = (tile & 3) * 16;        // o base within matrix
        const float* Wm = (m == 0) ? Wq : (m == 1) ? Wk : Wv;
        const float* wrow = Wm + (ol0 + lr) * 64;
#pragma unroll
        for (int ks = 0; ks < 2; ++ks) {
            const float4 w0 = *(const float4*)(wrow + lk + ks * 32);
            const float4 w1 = *(const float4*)(wrow + lk + ks * 32 + 4);
            const float wv8[8] = {w0.x, w0.y, w0.z, w0.w,
                                  w1.x, w1.y, w1.z, w1.w};
            short8 hi, lo;
#pragma unroll
            for (int j = 0; j < 8; ++j) {
                const unsigned short hh = f2bf(wv8[j]);
                hi[j] = (short)hh;
                lo[j] = (short)f2bf(wv8[j] - bf2f(hh));
            }
            ah[ot][ks] = hi;
            al[ot][ks] = lo;
        }
    }

    // ---- stage + convert x: 512 float4, 2 per thread, coalesced ----
    const float* xb = x + b * CHW;
#pragma unroll
    for (int i = 0; i < 2; ++i) {
        const int flat = t + i * 256;        // 0..511
        const int k    = flat >> 3;          // 8 float4 per k-row of 32
        const int n4   = (flat & 7) << 2;
        const float4 v = *(const float4*)(xb + k * HW + n0 + n4);
        const float vv[4] = {v.x, v.y, v.z, v.w};
#pragma unroll
        for (int j = 0; j < 4; ++j) {
            const unsigned short h = f2bf(vv[j]);
            sxh[n4 + j][k] = h;
            sxl[n4 + j][k] = f2bf(vv[j] - bf2f(h));
        }
    }
    __syncthreads();

    f32x4 acc[3][2];
#pragma unroll
    for (int ot = 0; ot < 3; ++ot)
#pragma unroll
        for (int nt = 0; nt < 2; ++nt) acc[ot][nt] = (f32x4)0.f;

#pragma unroll
    for (int nt = 0; nt < 2; ++nt) {
        const short8 bh0 = *(const short8*)&sxh[nt * 16 + lr][lk];
        const short8 bh1 = *(const short8*)&sxh[nt * 16 + lr][32 + lk];
        const short8 bl0 = *(const short8*)&sxl[nt * 16 + lr][lk];
        const short8 bl1 = *(const short8*)&sxl[nt * 16 + lr][32 + lk];
#pragma unroll
        for (int ot = 0; ot < 3; ++ot) {
            f32x4 d = acc[ot][nt];
            d = __builtin_amdgcn_mfma_f32_16x16x32_bf16(ah[ot][0], bh0, d, 0, 0, 0);
            d = __builtin_amdgcn_mfma_f32_16x16x32_bf16(ah[ot][1], bh1, d, 0, 0, 0);
            d = __builtin_amdgcn_mfma_f32_16x16x32_bf16(ah[ot][0], bl0, d, 0, 0, 0);
            d = __builtin_amdgcn_mfma_f32_16x16x32_bf16(ah[ot][1], bl1, d, 0, 0, 0);
            d = __builtin_amdgcn_mfma_f32_16x16x32_bf16(al[ot][0], bh0, d, 0, 0, 0);
            d = __builtin_amdgcn_mfma_f32_16x16x32_bf16(al[ot][1], bh1, d, 0, 0, 0);
            acc[ot][nt] = d;
        }
    }

    // ---- epilogue: q unpadded (pre-scaled); k/v into padded interior ----
#pragma unroll
    for (int ot = 0; ot < 3; ++ot) {
        const int tile = wv * 3 + ot;
        const int m    = tile >> 2;
        const int ol0  = (tile & 3) * 16;
        if (m == 0) {
            float* basep = qb + b * CHW + ol0 * HW + n0;
#pragma unroll
            for (int nt = 0; nt < 2; ++nt)
#pragma unroll
                for (int r = 0; r < 4; ++r) {
                    const int orow = (lane >> 4) * 4 + r;
                    basep[orow * HW + nt * 16 + lr] = acc[ot][nt][r] * LOG2E;
                }
        } else {
            float* ob = (m == 1) ? kb : vb;
            // padded pixel offset = flat + 2 rows = n0 + 128 (cols unchanged)
            float* basep = ob + (b * C + ol0) * PHW4 + n0 + 128;
#pragma unroll
            for (int nt = 0; nt < 2; ++nt)
#pragma unroll
                for (int r = 0; r < 4; ++r) {
                    const int orow = (lane >> 4) * 4 + r;
                    basep[orow * PHW4 + nt * 16 + lr] = acc[ot][nt][r];
                }
        }
    }
}

// ---------------------------------------------------------------------------
// Pass 2 (v15): attn — r27 packed-fp32 structure with UNCONDITIONAL stage:
// k/v are row-padded so staged row `row` maps to padded row h0+row in
// [0,67] always — the per-slot bounds compare/cndmask chain is gone.
// Column halo zero retained.  Everything else identical to r27.
// ---------------------------------------------------------------------------
__global__ __launch_bounds__(256) void attn_kernel(
    const float* __restrict__ qb,
    const float* __restrict__ kb,
    const float* __restrict__ vb,
    const float* __restrict__ rel_h,
    const float* __restrict__ rel_w,
    float* __restrict__ out)
{
    __shared__ __align__(16) float sk[SROWS3][SCOLS];   // 3.5 KB
    __shared__ __align__(16) float sv[SROWS3][SCOLS];   // 3.5 KB

    const int bid = blockIdx.x;
    const int b   = bid & 7;           // XCD co-residency: batch = XCD
    const int u   = bid >> 3;          // 0..511: c*8 + rowtile
    const int c   = u >> 3;
    const int pl  = b * C + c;
    const int h0  = (u & 7) * TROWS3;
    const int t   = threadIdx.x;

    const int lr = t >> 5;             // local row 0..7
    const int w0 = (t & 31) << 1;      // col base 0,2,..,62 (2 px)
    const int h  = h0 + lr;

    // hoisted loads: q (nt, pre-scaled by log2e) and bias row — both
    // overlap the stage latency below
    const f32x2 qe2 = __builtin_nontemporal_load(
        (const f32x2*)(qb + pl * HW + h * W + w0));
    const bool is_h = (c < (C / 2));
    const float* rp = is_h ? (rel_h + c * K) : (rel_w + (c - C / 2) * K);
    float r[K];
#pragma unroll
    for (int u2 = 0; u2 < K; ++u2) r[u2] = rp[u2];

    const float* kp = kb + pl * PHW4;
    const float* vp = vb + pl * PHW4;

    // ---- stage interior: 2 planes * (12 rows x 16 f4), UNCONDITIONAL ----
#pragma unroll
    for (int i = 0; i < 2; ++i) {
        const int s = t + i * 256;           // 0..511
        if (s < 2 * SROWS3 * 16) {           // 384
            const int p   = (s >= SROWS3 * 16);
            const int s2  = p ? s - SROWS3 * 16 : s;
            const int row = s2 >> 4;         // 0..11
            const int c4  = s2 & 15;         // f4 slot within row
            // padded row h0+row in [0,67] — always valid, pad rows are 0
            const float4 val =
                *(const float4*)((p ? vp : kp) + (h0 + row) * W + c4 * 4);
            float* dst = (p ? &sv[0][0] : &sk[0][0]) + row * SCOLS + 2 + c4 * 4;
            *(float2*)dst       = make_float2(val.x, val.y);
            *(float2*)(dst + 2) = make_float2(val.z, val.w);
        }
    }
    // ---- halo ring zero: cols {0,1},{66..71} of all 12 rows, both planes ----
    if (t < 2 * SROWS3 * 4) {          // 96
        const int p   = (t >= SROWS3 * 4);
        const int s   = p ? t - SROWS3 * 4 : t;
        const int row = s >> 2;              // 0..11
        const int e   = s & 3;               // 0 -> col 0; 1..3 -> 66,68,70
        const int col = (e == 0) ? 0 : (64 + 2 * e);
        float* dst = (p ? &sv[0][0] : &sk[0][0]) + row * SCOLS + col;
        *(float2*)dst = make_float2(0.f, 0.f);
    }
    __syncthreads();

    f32x2 den = {0.f, 0.f};
    f32x2 num = {0.f, 0.f};

    // px at global col w0+px; tap j reads LDS col (w0+px)+j  (interior at +2)
    if (is_h) {
#pragma unroll
        for (int i = 0; i < K; ++i) {
            const float2 k0 = *(const float2*)&sk[lr + i][w0];
            const float2 k1 = *(const float2*)&sk[lr + i][w0 + 2];
            const float2 k2 = *(const float2*)&sk[lr + i][w0 + 4];
            const float2 v0 = *(const float2*)&sv[lr + i][w0];
            const float2 v1 = *(const float2*)&sv[lr + i][w0 + 2];
            const float2 v2 = *(const float2*)&sv[lr + i][w0 + 4];
            const float kt[6] = {k0.x, k0.y, k1.x, k1.y, k2.x, k2.y};
            const float vt[6] = {v0.x, v0.y, v1.x, v1.y, v2.x, v2.y};
            const f32x2 qri = qe2 * r[i];                 // v_pk_mul
#pragma unroll
            for (int j = 0; j < K; ++j) {
                const f32x2 ktp = {kt[j], kt[j + 1]};
                const f32x2 vtp = {vt[j], vt[j + 1]};
                const f32x2 l = __builtin_elementwise_fma(qe2, ktp, qri);
                const f32x2 e = {fast_exp2(l.x), fast_exp2(l.y)};
                den += e;                                  // v_pk_add
                num = __builtin_elementwise_fma(e, vtp, num);  // v_pk_fma
            }
        }
    } else {
        f32x2 qrj[K];
#pragma unroll
        for (int j = 0; j < K; ++j) qrj[j] = qe2 * r[j];   // hoisted pk_mul
#pragma unroll
        for (int i = 0; i < K; ++i) {
            const float2 k0 = *(const float2*)&sk[lr + i][w0];
            const float2 k1 = *(const float2*)&sk[lr + i][w0 + 2];
            const float2 k2 = *(const float2*)&sk[lr + i][w0 + 4];
            const float2 v0 = *(const float2*)&sv[lr + i][w0];
            const float2 v1 = *(const float2*)&sv[lr + i][w0 + 2];
            const float2 v2 = *(const float2*)&sv[lr + i][w0 + 4];
            const float kt[6] = {k0.x, k0.y, k1.x, k1.y, k2.x, k2.y};
            const float vt[6] = {v0.x, v0.y, v1.x, v1.y, v2.x, v2.y};
#pragma unroll
            for (int j = 0; j < K; ++j) {
                const f32x2 ktp = {kt[j], kt[j + 1]};
                const f32x2 vtp = {vt[j], vt[j + 1]};
                const f32x2 l = __builtin_elementwise_fma(qe2, ktp, qrj[j]);
                const f32x2 e = {fast_exp2(l.x), fast_exp2(l.y)};
                den += e;
                num = __builtin_elementwise_fma(e, vtp, num);
            }
        }
    }

    f32x2 o;
    o.x = num.x * __builtin_amdgcn_rcpf(den.x);
    o.y = num.y * __builtin_amdgcn_rcpf(den.y);
    // nt store: out is never re-read on device; keep it out of L2
    __builtin_nontemporal_store(o, (f32x2*)(out + pl * HW + h * W + w0));
}

// ---------------------------------------------------------------------------
extern "C" void kernel_launch(void* const* d_in, const int* in_sizes, int n_in,
                              void* d_out, int out_size, void* d_ws, size_t ws_size,
                              hipStream_t stream)
{
    const float* x     = (const float*)d_in[0];
    const float* Wq    = (const float*)d_in[1];
    const float* Wk    = (const float*)d_in[2];
    const float* Wv    = (const float*)d_in[3];
    const float* rel_h = (const float*)d_in[4];
    const float* rel_w = (const float*)d_in[5];

    float* qb = (float*)d_ws;                 // [B,C,64,64]  8 MB (pre-scaled)
    float* kb = qb + TOT;                     // [B,C,68,64]  8.9 MB row-padded
    float* vb = kb + (size_t)B * C * PHW4;    // [B,C,68,64]  8.9 MB row-padded

    qkv_mfma<<<B * 128, 256, 0, stream>>>(x, Wq, Wk, Wv, qb, kb, vb);

    attn_kernel<<<B * C * 8, 256, 0, stream>>>(qb, kb, vb, rel_h, rel_w,
                                               (float*)d_out);
}

// Round 29
// 25.456 us; speedup vs baseline: 1.0207x; 1.0207x over previous
//
#include <hip/hip_runtime.h>
#include <hip/hip_bf16.h>

// Problem constants (from reference)
#define B 8
#define C 64
#define H 64
#define W 64
#define K 5
#define PAD 2
#define HW (H * W)          // 4096
#define CHW (C * HW)        // 262144
#define TOT (B * CHW)       // 2097152

// attn tiling (r21 shape): block = 8 rows x 64 cols; 2 px/thread; 4096 blocks
#define TROWS3 8
#define SROWS3 (TROWS3 + 2 * PAD)  // 12 staged rows
#define SCOLS 72                   // 64 + 2*PAD padded to 72 (16B row align)

#define LOG2E 1.44269504088896340736f

typedef __attribute__((ext_vector_type(8))) short short8;   // 8 bf16 = 4 VGPR
typedef __attribute__((ext_vector_type(4))) float f32x4;    // mfma accum
typedef __attribute__((ext_vector_type(2))) float f32x2;    // packed fp32

// native bf16 conversion (RNE; pairs lower to v_cvt_pk_bf16_f32)
__device__ inline unsigned short f2bf(float f) {
    __hip_bfloat16 h = __float2bfloat16(f);
    return *(unsigned short*)&h;
}
__device__ inline float bf2f(unsigned short u) {
    return __uint_as_float(((unsigned)u) << 16);
}

// raw v_exp_f32 (single instruction; inputs in [-40,40])
__device__ inline float fast_exp2(float x) {
    return __builtin_amdgcn_exp2f(x);
}

// ---------------------------------------------------------------------------
// Pass 1 (v12): qkv MFMA GEMM — best-measured config (r27, 25.54 us).
// A-frag prep hoisted above the stage; q pre-scaled by log2(e) in epilogue.
// ---------------------------------------------------------------------------
__global__ __launch_bounds__(256) void qkv_mfma(
    const float* __restrict__ x,
    const float* __restrict__ Wq,
    const float* __restrict__ Wk,
    const float* __restrict__ Wv,
    float* __restrict__ qb, float* __restrict__ kb, float* __restrict__ vb)
{
    __shared__ unsigned short sxh[32][72];   // [n][k], 4.6 KB
    __shared__ unsigned short sxl[32][72];

    const int bid = blockIdx.x;
    const int b   = bid & 7;             // XCD co-residency: batch = XCD
    const int n0  = (bid >> 3) * 32;     // hw base (128 chunks per batch)
    const int t   = threadIdx.x;

    const int lane = t & 63;
    const int wv   = __builtin_amdgcn_readfirstlane(t >> 6);  // wave id 0..3
    const int lr   = lane & 15;          // tile row (A) / col (B,D)
    const int lk   = (lane >> 4) * 8;    // k-group base

    // ---- A fragments FIRST (overlaps the x stage-load latency below) ----
    short8 ah[3][2], al[3][2];
#pragma unroll
    for (int ot = 0; ot < 3; ++ot) {
        const int tile = wv * 3 + ot;            // 0..11
        const int m    = tile >> 2;              // 0=q,1=k,2=v
        const int ol0  = (tile & 3) * 16;        // o base within matrix
        const float* Wm = (m == 0) ? Wq : (m == 1) ? Wk : Wv;
        const float* wrow = Wm + (ol0 + lr) * 64;
#pragma unroll
        for (int ks = 0; ks < 2; ++ks) {
            const float4 w0 = *(const float4*)(wrow + lk + ks * 32);
            const float4 w1 = *(const float4*)(wrow + lk + ks * 32 + 4);
            const float wv8[8] = {w0.x, w0.y, w0.z, w0.w,
                                  w1.x, w1.y, w1.z, w1.w};
            short8 hi, lo;
#pragma unroll
            for (int j = 0; j < 8; ++j) {
                const unsigned short hh = f2bf(wv8[j]);
                hi[j] = (short)hh;
                lo[j] = (short)f2bf(wv8[j] - bf2f(hh));
            }
            ah[ot][ks] = hi;
            al[ot][ks] = lo;
        }
    }

    // ---- stage + convert x: 512 float4, 2 per thread, coalesced ----
    const float* xb = x + b * CHW;
#pragma unroll
    for (int i = 0; i < 2; ++i) {
        const int flat = t + i * 256;        // 0..511
        const int k    = flat >> 3;          // 8 float4 per k-row of 32
        const int n4   = (flat & 7) << 2;
        const float4 v = *(const float4*)(xb + k * HW + n0 + n4);
        const float vv[4] = {v.x, v.y, v.z, v.w};
#pragma unroll
        for (int j = 0; j < 4; ++j) {
            const unsigned short h = f2bf(vv[j]);
            sxh[n4 + j][k] = h;
            sxl[n4 + j][k] = f2bf(vv[j] - bf2f(h));
        }
    }
    __syncthreads();

    f32x4 acc[3][2];
#pragma unroll
    for (int ot = 0; ot < 3; ++ot)
#pragma unroll
        for (int nt = 0; nt < 2; ++nt) acc[ot][nt] = (f32x4)0.f;

#pragma unroll
    for (int nt = 0; nt < 2; ++nt) {
        const short8 bh0 = *(const short8*)&sxh[nt * 16 + lr][lk];
        const short8 bh1 = *(const short8*)&sxh[nt * 16 + lr][32 + lk];
        const short8 bl0 = *(const short8*)&sxl[nt * 16 + lr][lk];
        const short8 bl1 = *(const short8*)&sxl[nt * 16 + lr][32 + lk];
#pragma unroll
        for (int ot = 0; ot < 3; ++ot) {
            f32x4 d = acc[ot][nt];
            d = __builtin_amdgcn_mfma_f32_16x16x32_bf16(ah[ot][0], bh0, d, 0, 0, 0);
            d = __builtin_amdgcn_mfma_f32_16x16x32_bf16(ah[ot][1], bh1, d, 0, 0, 0);
            d = __builtin_amdgcn_mfma_f32_16x16x32_bf16(ah[ot][0], bl0, d, 0, 0, 0);
            d = __builtin_amdgcn_mfma_f32_16x16x32_bf16(ah[ot][1], bl1, d, 0, 0, 0);
            d = __builtin_amdgcn_mfma_f32_16x16x32_bf16(al[ot][0], bh0, d, 0, 0, 0);
            d = __builtin_amdgcn_mfma_f32_16x16x32_bf16(al[ot][1], bh1, d, 0, 0, 0);
            acc[ot][nt] = d;
        }
    }

#pragma unroll
    for (int ot = 0; ot < 3; ++ot) {
        const int tile = wv * 3 + ot;
        const int m    = tile >> 2;
        const int ol0  = (tile & 3) * 16;
        float* ob = (m == 0) ? qb : (m == 1) ? kb : vb;
        const float scale = (m == 0) ? LOG2E : 1.0f;   // q pre-scaled for exp2
        float* basep = ob + b * CHW + ol0 * HW + n0;
#pragma unroll
        for (int nt = 0; nt < 2; ++nt)
#pragma unroll
            for (int r = 0; r < 4; ++r) {
                const int orow = (lane >> 4) * 4 + r;
                basep[orow * HW + nt * 16 + lr] = acc[ot][nt][r] * scale;
            }
    }
}

// ---------------------------------------------------------------------------
// Pass 2 (v14): attn — best-measured config (r27, 25.54 us).  Packed-fp32
// inner loop (v_pk_fma/v_pk_add), nt q-load/out-store, f4 stage with pow-2
// mapping, raw v_exp, 4096 light blocks, XCD co-residency swizzle.
// ---------------------------------------------------------------------------
__global__ __launch_bounds__(256) void attn_kernel(
    const float* __restrict__ qb,
    const float* __restrict__ kb,
    const float* __restrict__ vb,
    const float* __restrict__ rel_h,
    const float* __restrict__ rel_w,
    float* __restrict__ out)
{
    __shared__ __align__(16) float sk[SROWS3][SCOLS];   // 3.5 KB
    __shared__ __align__(16) float sv[SROWS3][SCOLS];   // 3.5 KB

    const int bid = blockIdx.x;
    const int b   = bid & 7;           // XCD co-residency: batch = XCD
    const int u   = bid >> 3;          // 0..511: c*8 + rowtile
    const int c   = u >> 3;
    const int pl  = b * C + c;
    const int h0  = (u & 7) * TROWS3;
    const int t   = threadIdx.x;

    const int lr = t >> 5;             // local row 0..7
    const int w0 = (t & 31) << 1;      // col base 0,2,..,62 (2 px)
    const int h  = h0 + lr;

    // hoisted loads: q (nt, pre-scaled by log2e) and bias row — both
    // overlap the stage latency below
    const f32x2 qe2 = __builtin_nontemporal_load(
        (const f32x2*)(qb + pl * HW + h * W + w0));
    const bool is_h = (c < (C / 2));
    const float* rp = is_h ? (rel_h + c * K) : (rel_w + (c - C / 2) * K);
    float r[K];
#pragma unroll
    for (int u2 = 0; u2 < K; ++u2) r[u2] = rp[u2];

    const float* kp = kb + pl * HW;
    const float* vp = vb + pl * HW;

    // ---- stage interior: 2 planes * (12 rows x 16 f4) = 384 slots ----
#pragma unroll
    for (int i = 0; i < 2; ++i) {
        const int s = t + i * 256;           // 0..511
        if (s < 2 * SROWS3 * 16) {           // 384
            const int p   = (s >= SROWS3 * 16);
            const int s2  = p ? s - SROWS3 * 16 : s;
            const int row = s2 >> 4;         // 0..11
            const int c4  = s2 & 15;         // f4 slot within row
            const int g   = h0 + row - PAD;  // global row
            float4 val = make_float4(0.f, 0.f, 0.f, 0.f);
            if ((unsigned)g < (unsigned)H)
                val = *(const float4*)((p ? vp : kp) + g * W + c4 * 4);
            float* dst = (p ? &sv[0][0] : &sk[0][0]) + row * SCOLS + 2 + c4 * 4;
            *(float2*)dst       = make_float2(val.x, val.y);
            *(float2*)(dst + 2) = make_float2(val.z, val.w);
        }
    }
    // ---- halo ring zero: cols {0,1},{66..71} of all 12 rows, both planes ----
    if (t < 2 * SROWS3 * 4) {          // 96
        const int p   = (t >= SROWS3 * 4);
        const int s   = p ? t - SROWS3 * 4 : t;
        const int row = s >> 2;              // 0..11
        const int e   = s & 3;               // 0 -> col 0; 1..3 -> 66,68,70
        const int col = (e == 0) ? 0 : (64 + 2 * e);
        float* dst = (p ? &sv[0][0] : &sk[0][0]) + row * SCOLS + col;
        *(float2*)dst = make_float2(0.f, 0.f);
    }
    __syncthreads();

    f32x2 den = {0.f, 0.f};
    f32x2 num = {0.f, 0.f};

    // px at global col w0+px; tap j reads LDS col (w0+px)+j  (interior at +2)
    if (is_h) {
#pragma unroll
        for (int i = 0; i < K; ++i) {
            const float2 k0 = *(const float2*)&sk[lr + i][w0];
            const float2 k1 = *(const float2*)&sk[lr + i][w0 + 2];
            const float2 k2 = *(const float2*)&sk[lr + i][w0 + 4];
            const float2 v0 = *(const float2*)&sv[lr + i][w0];
            const float2 v1 = *(const float2*)&sv[lr + i][w0 + 2];
            const float2 v2 = *(const float2*)&sv[lr + i][w0 + 4];
            const float kt[6] = {k0.x, k0.y, k1.x, k1.y, k2.x, k2.y};
            const float vt[6] = {v0.x, v0.y, v1.x, v1.y, v2.x, v2.y};
            const f32x2 qri = qe2 * r[i];                 // v_pk_mul
#pragma unroll
            for (int j = 0; j < K; ++j) {
                const f32x2 ktp = {kt[j], kt[j + 1]};
                const f32x2 vtp = {vt[j], vt[j + 1]};
                const f32x2 l = __builtin_elementwise_fma(qe2, ktp, qri);
                const f32x2 e = {fast_exp2(l.x), fast_exp2(l.y)};
                den += e;                                  // v_pk_add
                num = __builtin_elementwise_fma(e, vtp, num);  // v_pk_fma
            }
        }
    } else {
        f32x2 qrj[K];
#pragma unroll
        for (int j = 0; j < K; ++j) qrj[j] = qe2 * r[j];   // hoisted pk_mul
#pragma unroll
        for (int i = 0; i < K; ++i) {
            const float2 k0 = *(const float2*)&sk[lr + i][w0];
            const float2 k1 = *(const float2*)&sk[lr + i][w0 + 2];
            const float2 k2 = *(const float2*)&sk[lr + i][w0 + 4];
            const float2 v0 = *(const float2*)&sv[lr + i][w0];
            const float2 v1 = *(const float2*)&sv[lr + i][w0 + 2];
            const float2 v2 = *(const float2*)&sv[lr + i][w0 + 4];
            const float kt[6] = {k0.x, k0.y, k1.x, k1.y, k2.x, k2.y};
            const float vt[6] = {v0.x, v0.y, v1.x, v1.y, v2.x, v2.y};
#pragma unroll
            for (int j = 0; j < K; ++j) {
                const f32x2 ktp = {kt[j], kt[j + 1]};
                const f32x2 vtp = {vt[j], vt[j + 1]};
                const f32x2 l = __builtin_elementwise_fma(qe2, ktp, qrj[j]);
                const f32x2 e = {fast_exp2(l.x), fast_exp2(l.y)};
                den += e;
                num = __builtin_elementwise_fma(e, vtp, num);
            }
        }
    }

    f32x2 o;
    o.x = num.x * __builtin_amdgcn_rcpf(den.x);
    o.y = num.y * __builtin_amdgcn_rcpf(den.y);
    // nt store: out is never re-read on device; keep it out of L2
    __builtin_nontemporal_store(o, (f32x2*)(out + pl * HW + h * W + w0));
}

// ---------------------------------------------------------------------------
extern "C" void kernel_launch(void* const* d_in, const int* in_sizes, int n_in,
                              void* d_out, int out_size, void* d_ws, size_t ws_size,
                              hipStream_t stream)
{
    const float* x     = (const float*)d_in[0];
    const float* Wq    = (const float*)d_in[1];
    const float* Wk    = (const float*)d_in[2];
    const float* Wv    = (const float*)d_in[3];
    const float* rel_h = (const float*)d_in[4];
    const float* rel_w = (const float*)d_in[5];

    float* qb = (float*)d_ws;        // [B,C,64,64]  8 MB  (q pre-scaled)
    float* kb = qb + TOT;            // [B,C,64,64]  8 MB
    float* vb = kb + TOT;            // [B,C,64,64]  8 MB

    qkv_mfma<<<B * 128, 256, 0, stream>>>(x, Wq, Wk, Wv, qb, kb, vb);

    attn_kernel<<<B * C * 8, 256, 0, stream>>>(qb, kb, vb, rel_h, rel_w,
                                               (float*)d_out);
}